// Round 12
// baseline (155.174 us; speedup 1.0000x reference)
//
#include <hip/hip_runtime.h>
#include <cstddef>

// Problem constants
#define Bsz 2
#define Lr  2048
#define Dr  1024
#define Nr  16
#define M_ROWS (Bsz*Lr)          // 4096
#define NPAD   1088              // padded (W_dt | W_B | W_C | zeros), 17 tiles of 64
#define CHUNK  16
#define NCH    (Lr/CHUNK)        // 128

#define BM 128
#define BN 64
#define BK 64
#define NK (Dr/BK)               // 16 K-iterations

typedef __attribute__((ext_vector_type(8))) __bf16 bf16x8;
typedef __attribute__((ext_vector_type(4))) float floatx4;

__device__ __forceinline__ unsigned short f2bf(float f) {
    unsigned u = __float_as_uint(f);
    u += 0x7fffu + ((u >> 16) & 1u);
    return (unsigned short)(u >> 16);
}

__device__ __forceinline__ float bf2f(unsigned short u) {
    return __uint_as_float(((unsigned)u) << 16);
}

__device__ __forceinline__ float softplus_f(float x) {
    // abs threshold is 0.905 -> fast log is fine
    if (x > 0.f) return x + __logf(1.f + __expf(-x));
    return __logf(1.f + __expf(x));
}

__device__ __forceinline__ void gload_lds16(const unsigned short* g, unsigned short* l) {
    __builtin_amdgcn_global_load_lds((const __attribute__((address_space(1))) void*)g,
                                     (__attribute__((address_space(3))) void*)l, 16, 0, 0);
}

// ---------------- K0: fused LayerNorm (blocks 0..4095) + weight-pack (rest) ----------------
__global__ __launch_bounds__(256) void ln_pack_kernel(const float* __restrict__ x,
                                                      const float* __restrict__ gamma,
                                                      const float* __restrict__ beta,
                                                      unsigned short* __restrict__ xnb,
                                                      const float* __restrict__ Wdt,
                                                      const float* __restrict__ WB,
                                                      const float* __restrict__ WC,
                                                      unsigned short* __restrict__ Wcat) {
    if (blockIdx.x >= M_ROWS) {
        int i = (blockIdx.x - M_ROWS) * 256 + threadIdx.x;  // over NPAD*Dr
        int row = i >> 10;
        int col = i & 1023;
        float v;
        if (row < Dr)                 v = Wdt[i];
        else if (row < Dr + Nr)       v = WB[(row - Dr) * Dr + col];
        else if (row < Dr + 2*Nr)     v = WC[(row - Dr - Nr) * Dr + col];
        else                          v = 0.f;
        Wcat[i] = f2bf(v);
        return;
    }
    int row = blockIdx.x;
    int tid = threadIdx.x;
    const float4* xr = (const float4*)(x + (size_t)row * Dr);
    float4 v = xr[tid];
    float s  = v.x + v.y + v.z + v.w;
    float ss = v.x*v.x + v.y*v.y + v.z*v.z + v.w*v.w;
    #pragma unroll
    for (int off = 32; off > 0; off >>= 1) {
        s  += __shfl_down(s, off);
        ss += __shfl_down(ss, off);
    }
    __shared__ float red[8];
    int wid = tid >> 6;
    if ((tid & 63) == 0) { red[wid*2] = s; red[wid*2+1] = ss; }
    __syncthreads();
    if (tid == 0) {
        float S = 0.f, SS = 0.f;
        #pragma unroll
        for (int w = 0; w < 4; w++) { S += red[w*2]; SS += red[w*2+1]; }
        float mu  = S * (1.f/Dr);
        float var = SS * (1.f/Dr) - mu*mu;
        red[0] = mu;
        red[1] = rsqrtf(var + 1e-5f);
    }
    __syncthreads();
    float mu = red[0], rs = red[1];
    float4 g = ((const float4*)gamma)[tid], bt = ((const float4*)beta)[tid];
    float4 o;
    o.x = (v.x - mu) * rs * g.x + bt.x;
    o.y = (v.y - mu) * rs * g.y + bt.y;
    o.z = (v.z - mu) * rs * g.z + bt.z;
    o.w = (v.w - mu) * rs * g.w + bt.w;
    ushort4 ob;
    ob.x = f2bf(o.x); ob.y = f2bf(o.y); ob.z = f2bf(o.z); ob.w = f2bf(o.w);
    ((ushort4*)(xnb + (size_t)row * Dr))[tid] = ob;
}

// ---------------- K2: MFMA GEMM [M_ROWS x NPAD] = xnb @ Wcat^T ----------------
// BM=128 x BN=64: 4 waves each own 64x32 (4x2 acc), 16 MFMA/wave/iter per
// 24 KB staged (FLOP:LDS-byte 43 vs 32 for the 64x64 config) -- more compute
// amortizing each barrier drain. 544 blocks = 2.1/CU. Keeps: XOR-swizzled LDS
// (conflict-free, proven R10/R11), XCD colocation of A-tile sharers, k-stagger.
__global__ __launch_bounds__(256) void gemm_kernel(const unsigned short* __restrict__ xnb,
                                                   const unsigned short* __restrict__ w,
                                                   const float* __restrict__ b_dt,
                                                   unsigned short* __restrict__ dt,
                                                   float* __restrict__ bin,
                                                   float* __restrict__ cin) {
    __shared__ unsigned short As[BM * BK];  // 16 KB, swizzled [128 rows][8 slots of 8]
    __shared__ unsigned short Bs[BN * BK];  // 8 KB
    int tid  = threadIdx.x;
    int wave = tid >> 6;
    int lane = tid & 63;
    int lm   = lane & 15;
    int quad = lane >> 4;
    int bid  = blockIdx.x;             // 544 blocks = 8 XCD-lanes x 68
    int xcd  = bid & 7;
    int j0   = bid >> 3;               // 0..67
    int nt   = j0 % 17;
    int mt   = (j0 / 17) * 8 + xcd;    // 0..31; 17 blocks sharing an A-tile on one XCD
    int Mb = mt * BM;
    int Nb = nt * BN;
    int wm = (wave >> 1) * 64;         // {0, 64} within the 128-row tile
    int wn = (wave & 1)  * 32;         // {0, 32} within the 64-col tile
    int koff = (mt + nt) & (NK - 1);

    // staging: A has 1024 16B-slots (4/thread), B has 512 (2/thread);
    // slot c = (row=c>>3, cs=c&7) holds global chunk cg = cs ^ (row&7).
    const unsigned short* AgP[4];
    unsigned short*       AlP[4];
    #pragma unroll
    for (int q = 0; q < 4; q++) {
        int c = tid + 256 * q;
        int r = c >> 3, cg = (c & 7) ^ (r & 7);
        AgP[q] = xnb + (size_t)(Mb + r) * Dr + cg * 8;
        AlP[q] = &As[(size_t)c * 8];
    }
    const unsigned short* BgP[2];
    unsigned short*       BlP[2];
    #pragma unroll
    for (int q = 0; q < 2; q++) {
        int c = tid + 256 * q;
        int r = c >> 3, cg = (c & 7) ^ (r & 7);
        BgP[q] = w + (size_t)(Nb + r) * Dr + cg * 8;
        BlP[q] = &Bs[(size_t)c * 8];
    }

    floatx4 acc[4][2] = {};

    for (int kk = 0; kk < NK; kk++) {
        int k0 = ((kk + koff) & (NK - 1)) * BK;
        #pragma unroll
        for (int q = 0; q < 4; q++) gload_lds16(AgP[q] + k0, AlP[q]);
        #pragma unroll
        for (int q = 0; q < 2; q++) gload_lds16(BgP[q] + k0, BlP[q]);
        __syncthreads();   // drains vmcnt -> LDS valid
        #pragma unroll
        for (int s = 0; s < 2; s++) {
            int cg = s * 4 + quad;
            bf16x8 a[4], b[2];
            #pragma unroll
            for (int i = 0; i < 4; i++) {
                int r = wm + i * 16 + lm;
                a[i] = *(const bf16x8*)&As[r * BK + ((cg ^ (r & 7)) * 8)];
            }
            #pragma unroll
            for (int j = 0; j < 2; j++) {
                int r = wn + j * 16 + lm;
                b[j] = *(const bf16x8*)&Bs[r * BK + ((cg ^ (r & 7)) * 8)];
            }
            #pragma unroll
            for (int i = 0; i < 4; i++)
                #pragma unroll
                for (int j = 0; j < 2; j++)
                    acc[i][j] = __builtin_amdgcn_mfma_f32_16x16x32_bf16(a[i], b[j], acc[i][j], 0, 0, 0);
        }
        __syncthreads();   // before next-iter overwrite
    }

    // C/D layout: col = lane&15, row = (lane>>4)*4 + reg   [m89/m91]
    #pragma unroll
    for (int i = 0; i < 4; i++) {
        int grow0 = Mb + wm + i * 16 + quad * 4;
        #pragma unroll
        for (int jj = 0; jj < 2; jj++) {
            int gcol = Nb + wn + jj * 16 + lm;
            #pragma unroll
            for (int r = 0; r < 4; r++) {
                float v = acc[i][jj][r];
                int row = grow0 + r;
                if (gcol < Dr) {
                    dt[(size_t)row * Dr + gcol] = f2bf(softplus_f(v + b_dt[gcol]));
                } else if (gcol < Dr + Nr) {
                    bin[(size_t)row * Nr + (gcol - Dr)] = v;
                } else if (gcol < Dr + 2*Nr) {
                    cin[(size_t)row * Nr + (gcol - Dr - Nr)] = v;
                }
            }
        }
    }
}

// ---------------- K3: scan pass 1 (per-chunk local scan; emit S, h_end) ----------------
// P is fully determined by S = sum(dt): store the scalar S (1 MB f32) instead
// of P[16] (8 MB bf16); combine recomputes exp(S*ac[n]) -- 4.2M cheap exps.
__global__ __launch_bounds__(256) void scan1_kernel(const unsigned short* __restrict__ dtb,
                                                    const unsigned short* __restrict__ xnb,
                                                    const float* __restrict__ bin,
                                                    const float* __restrict__ A_log,
                                                    float* __restrict__ Sws,
                                                    unsigned short* __restrict__ hendws) {
    int tid = threadIdx.x;
    int d  = blockIdx.x * 256 + tid;
    int ch = blockIdx.y;
    int b  = blockIdx.z;
    size_t rowbase = (size_t)b * Lr + ch * CHUNK;

    float ac[16];
    #pragma unroll
    for (int i = 0; i < 4; i++) {
        float4 t = ((const float4*)(A_log + (size_t)d * Nr))[i];
        ac[i*4+0] = -__expf(t.x);
        ac[i*4+1] = -__expf(t.y);
        ac[i*4+2] = -__expf(t.z);
        ac[i*4+3] = -__expf(t.w);
    }

    __shared__ float lb[CHUNK * Nr];   // 256 floats: one per thread
    lb[tid] = bin[rowbase * Nr + tid];
    __syncthreads();

    // full register batch: 32 loads in flight
    float dtv[CHUNK], xv[CHUNK];
    {
        const unsigned short* dtp = dtb + rowbase * Dr + d;
        const unsigned short* xp  = xnb + rowbase * Dr + d;
        #pragma unroll
        for (int t = 0; t < CHUNK; t++) {
            dtv[t] = bf2f(dtp[(size_t)t * Dr]);
            xv[t]  = bf2f(xp[(size_t)t * Dr]);
        }
    }

    float h[16];
    #pragma unroll
    for (int n = 0; n < 16; n++) h[n] = 0.f;
    float S = 0.f;

    #pragma unroll
    for (int t = 0; t < CHUNK; t++) {
        float dv = dtv[t];
        S += dv;
        float cm = dv * xv[t];
        const float4* br4 = (const float4*)(lb + t * Nr);
        float4 q0 = br4[0], q1 = br4[1], q2 = br4[2], q3 = br4[3];
        float bb[16] = {q0.x,q0.y,q0.z,q0.w, q1.x,q1.y,q1.z,q1.w,
                        q2.x,q2.y,q2.z,q2.w, q3.x,q3.y,q3.z,q3.w};
        #pragma unroll
        for (int n = 0; n < 16; n++)
            h[n] = __expf(dv * ac[n]) * h[n] + cm * bb[n];
    }

    Sws[(size_t)(b * NCH + ch) * Dr + d] = S;
    size_t obase = ((size_t)(b * NCH + ch) * Nr) * Dr + d;   // [b][ch][n][d]
    #pragma unroll
    for (int n = 0; n < 16; n++)
        hendws[obase + (size_t)n * Dr] = f2bf(h[n]);
}

// ---------------- K4: combine chunk states sequentially (S-recompute, batch-8) ----------------
__global__ __launch_bounds__(256) void combine_kernel(const float* __restrict__ Sws,
                                                      const unsigned short* __restrict__ hendws,
                                                      const float* __restrict__ A_log,
                                                      unsigned short* __restrict__ hinws) {
    int id = blockIdx.x * 256 + threadIdx.x;  // B*N*D = 32768
    int b  = id >> 14;
    int dn = id & 16383;                      // n*Dr + d
    int n  = dn >> 10;
    int d  = dn & 1023;
    float ac = -__expf(A_log[d * Nr + n]);
    size_t sbase = (size_t)b * NCH * Dr + d;
    size_t base  = (size_t)b * NCH * (Nr * Dr) + dn;
    float hin = 0.f;
    for (int cb = 0; cb < NCH; cb += 8) {
        float S8[8], he[8];
        #pragma unroll
        for (int u = 0; u < 8; u++) {
            S8[u] = Sws[sbase + (size_t)(cb + u) * Dr];
            he[u] = bf2f(hendws[base + (size_t)(cb + u) * (Nr * Dr)]);
        }
        #pragma unroll
        for (int u = 0; u < 8; u++) {
            size_t idx = base + (size_t)(cb + u) * (Nr * Dr);
            hinws[idx] = f2bf(hin);
            hin = __expf(S8[u] * ac) * hin + he[u];
        }
    }
}

// ---------------- K5: scan pass 2 (re-scan with h_in; emit y + D*residual) ----------------
__global__ __launch_bounds__(256) void scan2_kernel(const unsigned short* __restrict__ dtb,
                                                    const unsigned short* __restrict__ xnb,
                                                    const float* __restrict__ bin,
                                                    const float* __restrict__ cin,
                                                    const float* __restrict__ A_log,
                                                    const unsigned short* __restrict__ hinws,
                                                    const float* __restrict__ x,
                                                    const float* __restrict__ Dp,
                                                    float* __restrict__ out) {
    int tid = threadIdx.x;
    int d  = blockIdx.x * 256 + tid;
    int ch = blockIdx.y;
    int b  = blockIdx.z;
    size_t rowbase = (size_t)b * Lr + ch * CHUNK;

    float ac[16];
    #pragma unroll
    for (int i = 0; i < 4; i++) {
        float4 t = ((const float4*)(A_log + (size_t)d * Nr))[i];
        ac[i*4+0] = -__expf(t.x);
        ac[i*4+1] = -__expf(t.y);
        ac[i*4+2] = -__expf(t.z);
        ac[i*4+3] = -__expf(t.w);
    }

    __shared__ float lb[CHUNK * Nr];
    __shared__ float lc[CHUNK * Nr];
    lb[tid] = bin[rowbase * Nr + tid];
    lc[tid] = cin[rowbase * Nr + tid];
    __syncthreads();

    // full register batches in flight
    float dtv[CHUNK], xv[CHUNK];
    {
        const unsigned short* dtp = dtb + rowbase * Dr + d;
        const unsigned short* xp  = xnb + rowbase * Dr + d;
        #pragma unroll
        for (int t = 0; t < CHUNK; t++) {
            dtv[t] = bf2f(dtp[(size_t)t * Dr]);
            xv[t]  = bf2f(xp[(size_t)t * Dr]);
        }
    }

    size_t obase = ((size_t)(b * NCH + ch) * Nr) * Dr + d;
    float h[16];
    #pragma unroll
    for (int n = 0; n < 16; n++) h[n] = bf2f(hinws[obase + (size_t)n * Dr]);

    float dp = Dp[d];
    const float* xr = x   + rowbase * Dr + d;
    float* op       = out + rowbase * Dr + d;

    for (int tb = 0; tb < CHUNK; tb += 4) {
        float xr4[4];
        #pragma unroll
        for (int u = 0; u < 4; u++) xr4[u] = xr[(size_t)(tb + u) * Dr];
        #pragma unroll
        for (int u = 0; u < 4; u++) {
            int t = tb + u;
            float dv = dtv[t];
            float cm = dv * xv[t];
            const float4* br4 = (const float4*)(lb + t * Nr);
            const float4* cr4 = (const float4*)(lc + t * Nr);
            float4 q0 = br4[0], q1 = br4[1], q2 = br4[2], q3 = br4[3];
            float4 r0 = cr4[0], r1 = cr4[1], r2 = cr4[2], r3 = cr4[3];
            float bb[16] = {q0.x,q0.y,q0.z,q0.w, q1.x,q1.y,q1.z,q1.w,
                            q2.x,q2.y,q2.z,q2.w, q3.x,q3.y,q3.z,q3.w};
            float cc[16] = {r0.x,r0.y,r0.z,r0.w, r1.x,r1.y,r1.z,r1.w,
                            r2.x,r2.y,r2.z,r2.w, r3.x,r3.y,r3.z,r3.w};
            float y = 0.f;
            #pragma unroll
            for (int n = 0; n < 16; n++) {
                h[n] = __expf(dv * ac[n]) * h[n] + cm * bb[n];
                y += cc[n] * h[n];
            }
            op[(size_t)t * Dr] = y + dp * xr4[u];
        }
    }
}

// ---------------- host ----------------
extern "C" void kernel_launch(void* const* d_in, const int* in_sizes, int n_in,
                              void* d_out, int out_size, void* d_ws, size_t ws_size,
                              hipStream_t stream) {
    const float* x      = (const float*)d_in[0];
    const float* W_dt   = (const float*)d_in[1];
    const float* b_dt   = (const float*)d_in[2];
    const float* W_B    = (const float*)d_in[3];
    const float* W_C    = (const float*)d_in[4];
    const float* Dparam = (const float*)d_in[5];
    const float* A_log  = (const float*)d_in[6];
    const float* gamma  = (const float*)d_in[7];
    const float* beta   = (const float*)d_in[8];
    float* out = (float*)d_out;

    char* ws = (char*)d_ws;
    unsigned short* xnb  = (unsigned short*)(ws);                     // 8 MB
    unsigned short* wcat = (unsigned short*)(ws + 8388608);           // 2.125 MB
    unsigned short* dtb  = (unsigned short*)(ws + 10616832);          // 8 MB (bf16)
    float*          bin  = (float*)(ws + 19005440);                   // 256 KB
    float*          cin  = (float*)(ws + 19267584);                   // 256 KB
    float*          Sws  = (float*)(ws + 19529728);                   // 1 MB (f32 chunk dt-sums)
    unsigned short* hend = (unsigned short*)(ws + 20578304);          // 8 MB (bf16)
    unsigned short* hin  = (unsigned short*)(ws + 28966912);          // 8 MB  (total ~37 MB)

    ln_pack_kernel<<<M_ROWS + (NPAD * Dr) / 256, 256, 0, stream>>>(
        x, gamma, beta, xnb, W_dt, W_B, W_C, wcat);
    gemm_kernel<<<(M_ROWS / BM) * (NPAD / BN), 256, 0, stream>>>(xnb, wcat, b_dt, dtb, bin, cin);
    dim3 sgrid(Dr / 256, NCH, Bsz);
    scan1_kernel<<<sgrid, 256, 0, stream>>>(dtb, xnb, bin, A_log, Sws, hend);
    combine_kernel<<<(Bsz * Dr * Nr) / 256, 256, 0, stream>>>(Sws, hend, A_log, hin);
    scan2_kernel<<<sgrid, 256, 0, stream>>>(dtb, xnb, bin, cin, A_log, hin, x, Dparam, out);
}

// Round 13
// 149.809 us; speedup vs baseline: 1.0358x; 1.0358x over previous
//
#include <hip/hip_runtime.h>
#include <cstddef>

// Problem constants
#define Bsz 2
#define Lr  2048
#define Dr  1024
#define Nr  16
#define M_ROWS (Bsz*Lr)          // 4096
#define NPAD   1088              // padded (W_dt | W_B | W_C | zeros), 17 tiles of 64
#define CHUNK  16
#define NCH    (Lr/CHUNK)        // 128

#define BM 64
#define BN 64
#define BK 64
#define NK (Dr/BK)               // 16 K-iterations

typedef __attribute__((ext_vector_type(8))) __bf16 bf16x8;
typedef __attribute__((ext_vector_type(4))) float floatx4;

__device__ __forceinline__ unsigned short f2bf(float f) {
    unsigned u = __float_as_uint(f);
    u += 0x7fffu + ((u >> 16) & 1u);
    return (unsigned short)(u >> 16);
}

__device__ __forceinline__ float bf2f(unsigned short u) {
    return __uint_as_float(((unsigned)u) << 16);
}

__device__ __forceinline__ float softplus_f(float x) {
    // abs threshold is 0.905 -> fast log is fine
    if (x > 0.f) return x + __logf(1.f + __expf(-x));
    return __logf(1.f + __expf(x));
}

__device__ __forceinline__ void gload_lds16(const unsigned short* g, unsigned short* l) {
    __builtin_amdgcn_global_load_lds((const __attribute__((address_space(1))) void*)g,
                                     (__attribute__((address_space(3))) void*)l, 16, 0, 0);
}

// ---------------- K0: fused LayerNorm (blocks 0..4095) + weight-pack (rest) ----------------
__global__ __launch_bounds__(256) void ln_pack_kernel(const float* __restrict__ x,
                                                      const float* __restrict__ gamma,
                                                      const float* __restrict__ beta,
                                                      unsigned short* __restrict__ xnb,
                                                      const float* __restrict__ Wdt,
                                                      const float* __restrict__ WB,
                                                      const float* __restrict__ WC,
                                                      unsigned short* __restrict__ Wcat) {
    if (blockIdx.x >= M_ROWS) {
        int i = (blockIdx.x - M_ROWS) * 256 + threadIdx.x;  // over NPAD*Dr
        int row = i >> 10;
        int col = i & 1023;
        float v;
        if (row < Dr)                 v = Wdt[i];
        else if (row < Dr + Nr)       v = WB[(row - Dr) * Dr + col];
        else if (row < Dr + 2*Nr)     v = WC[(row - Dr - Nr) * Dr + col];
        else                          v = 0.f;
        Wcat[i] = f2bf(v);
        return;
    }
    int row = blockIdx.x;
    int tid = threadIdx.x;
    const float4* xr = (const float4*)(x + (size_t)row * Dr);
    float4 v = xr[tid];
    float s  = v.x + v.y + v.z + v.w;
    float ss = v.x*v.x + v.y*v.y + v.z*v.z + v.w*v.w;
    #pragma unroll
    for (int off = 32; off > 0; off >>= 1) {
        s  += __shfl_down(s, off);
        ss += __shfl_down(ss, off);
    }
    __shared__ float red[8];
    int wid = tid >> 6;
    if ((tid & 63) == 0) { red[wid*2] = s; red[wid*2+1] = ss; }
    __syncthreads();
    if (tid == 0) {
        float S = 0.f, SS = 0.f;
        #pragma unroll
        for (int w = 0; w < 4; w++) { S += red[w*2]; SS += red[w*2+1]; }
        float mu  = S * (1.f/Dr);
        float var = SS * (1.f/Dr) - mu*mu;
        red[0] = mu;
        red[1] = rsqrtf(var + 1e-5f);
    }
    __syncthreads();
    float mu = red[0], rs = red[1];
    float4 g = ((const float4*)gamma)[tid], bt = ((const float4*)beta)[tid];
    float4 o;
    o.x = (v.x - mu) * rs * g.x + bt.x;
    o.y = (v.y - mu) * rs * g.y + bt.y;
    o.z = (v.z - mu) * rs * g.z + bt.z;
    o.w = (v.w - mu) * rs * g.w + bt.w;
    ushort4 ob;
    ob.x = f2bf(o.x); ob.y = f2bf(o.y); ob.z = f2bf(o.z); ob.w = f2bf(o.w);
    ((ushort4*)(xnb + (size_t)row * Dr))[tid] = ob;
}

// ---------------- K2: MFMA GEMM [M_ROWS x NPAD] = xnb @ Wcat^T ----------------
// FROZEN R11 config (149.6us total): 4-wave 64x64, BK=64, XOR-swizzled LDS
// (conflict-free frag reads), XCD colocation of A-tile sharers, k-stagger,
// bf16 dt output. R12's BM=128 variant (544 blocks = 2.1/CU) regressed +5us:
// on this small GEMM, block count >= ~4/CU beats per-block intensity.
__global__ __launch_bounds__(256) void gemm_kernel(const unsigned short* __restrict__ xnb,
                                                   const unsigned short* __restrict__ w,
                                                   const float* __restrict__ b_dt,
                                                   unsigned short* __restrict__ dt,
                                                   float* __restrict__ bin,
                                                   float* __restrict__ cin) {
    __shared__ unsigned short As[BM * BK];  // 8 KB, swizzled [64 rows][8 slots of 8]
    __shared__ unsigned short Bs[BN * BK];  // 8 KB
    int tid  = threadIdx.x;
    int wave = tid >> 6;
    int lane = tid & 63;
    int lm   = lane & 15;
    int quad = lane >> 4;
    int bid  = blockIdx.x;             // 1088 blocks = 8 XCD-lanes x 136
    int xcd  = bid & 7;
    int j0   = bid >> 3;               // 0..135
    int nt   = j0 % 17;
    int mt   = (j0 / 17) * 8 + xcd;    // 0..63
    int Mb = mt * BM;
    int Nb = nt * BN;
    int wm = (wave >> 1) * 32;
    int wn = (wave & 1)  * 32;
    int koff = (mt + nt) & (NK - 1);

    // staging: thread t fills slots c0=t, c1=t+256; slot c = (row=c>>3, cs=c&7)
    // holds global chunk cg = cs ^ (row&7).
    int r0 = tid >> 3,         cg0 = (tid & 7) ^ (r0 & 7);
    int r1 = (tid + 256) >> 3, cg1 = ((tid + 256) & 7) ^ (r1 & 7);
    const unsigned short* Ag0 = xnb + (size_t)(Mb + r0) * Dr + cg0 * 8;
    const unsigned short* Ag1 = xnb + (size_t)(Mb + r1) * Dr + cg1 * 8;
    const unsigned short* Bg0 = w   + (size_t)(Nb + r0) * Dr + cg0 * 8;
    const unsigned short* Bg1 = w   + (size_t)(Nb + r1) * Dr + cg1 * 8;
    unsigned short* Al0 = &As[(size_t)tid * 8];
    unsigned short* Al1 = &As[(size_t)(tid + 256) * 8];
    unsigned short* Bl0 = &Bs[(size_t)tid * 8];
    unsigned short* Bl1 = &Bs[(size_t)(tid + 256) * 8];

    floatx4 acc[2][2] = {};

    for (int kk = 0; kk < NK; kk++) {
        int k0 = ((kk + koff) & (NK - 1)) * BK;
        gload_lds16(Ag0 + k0, Al0);
        gload_lds16(Ag1 + k0, Al1);
        gload_lds16(Bg0 + k0, Bl0);
        gload_lds16(Bg1 + k0, Bl1);
        __syncthreads();   // drains vmcnt -> LDS valid
        #pragma unroll
        for (int s = 0; s < 2; s++) {
            int ra0 = wm + lm, ra1 = wm + 16 + lm;
            int rb0 = wn + lm, rb1 = wn + 16 + lm;
            int cg = s * 4 + quad;
            bf16x8 a0 = *(const bf16x8*)&As[ra0 * BK + ((cg ^ (ra0 & 7)) * 8)];
            bf16x8 a1 = *(const bf16x8*)&As[ra1 * BK + ((cg ^ (ra1 & 7)) * 8)];
            bf16x8 b0 = *(const bf16x8*)&Bs[rb0 * BK + ((cg ^ (rb0 & 7)) * 8)];
            bf16x8 b1 = *(const bf16x8*)&Bs[rb1 * BK + ((cg ^ (rb1 & 7)) * 8)];
            acc[0][0] = __builtin_amdgcn_mfma_f32_16x16x32_bf16(a0, b0, acc[0][0], 0, 0, 0);
            acc[0][1] = __builtin_amdgcn_mfma_f32_16x16x32_bf16(a0, b1, acc[0][1], 0, 0, 0);
            acc[1][0] = __builtin_amdgcn_mfma_f32_16x16x32_bf16(a1, b0, acc[1][0], 0, 0, 0);
            acc[1][1] = __builtin_amdgcn_mfma_f32_16x16x32_bf16(a1, b1, acc[1][1], 0, 0, 0);
        }
        __syncthreads();   // before next-iter overwrite
    }

    // C/D layout: col = lane&15, row = (lane>>4)*4 + reg   [m89/m91]
    #pragma unroll
    for (int i = 0; i < 2; i++) {
        int grow0 = Mb + wm + i * 16 + quad * 4;
        #pragma unroll
        for (int jj = 0; jj < 2; jj++) {
            int gcol = Nb + wn + jj * 16 + lm;
            #pragma unroll
            for (int r = 0; r < 4; r++) {
                float v = acc[i][jj][r];
                int row = grow0 + r;
                if (gcol < Dr) {
                    dt[(size_t)row * Dr + gcol] = f2bf(softplus_f(v + b_dt[gcol]));
                } else if (gcol < Dr + Nr) {
                    bin[(size_t)row * Nr + (gcol - Dr)] = v;
                } else if (gcol < Dr + 2*Nr) {
                    cin[(size_t)row * Nr + (gcol - Dr - Nr)] = v;
                }
            }
        }
    }
}

// ---------------- K3: scan pass 1 (per-chunk local scan; emit S, h_end) ----------------
// P is fully determined by S = sum(dt): store the scalar S (1 MB f32) instead
// of P[16] (8 MB bf16); combine recomputes exp(S*ac[n]).
__global__ __launch_bounds__(256) void scan1_kernel(const unsigned short* __restrict__ dtb,
                                                    const unsigned short* __restrict__ xnb,
                                                    const float* __restrict__ bin,
                                                    const float* __restrict__ A_log,
                                                    float* __restrict__ Sws,
                                                    unsigned short* __restrict__ hendws) {
    int tid = threadIdx.x;
    int d  = blockIdx.x * 256 + tid;
    int ch = blockIdx.y;
    int b  = blockIdx.z;
    size_t rowbase = (size_t)b * Lr + ch * CHUNK;

    float ac[16];
    #pragma unroll
    for (int i = 0; i < 4; i++) {
        float4 t = ((const float4*)(A_log + (size_t)d * Nr))[i];
        ac[i*4+0] = -__expf(t.x);
        ac[i*4+1] = -__expf(t.y);
        ac[i*4+2] = -__expf(t.z);
        ac[i*4+3] = -__expf(t.w);
    }

    __shared__ float lb[CHUNK * Nr];   // 256 floats: one per thread
    lb[tid] = bin[rowbase * Nr + tid];
    __syncthreads();

    // full register batch: 32 loads in flight
    float dtv[CHUNK], xv[CHUNK];
    {
        const unsigned short* dtp = dtb + rowbase * Dr + d;
        const unsigned short* xp  = xnb + rowbase * Dr + d;
        #pragma unroll
        for (int t = 0; t < CHUNK; t++) {
            dtv[t] = bf2f(dtp[(size_t)t * Dr]);
            xv[t]  = bf2f(xp[(size_t)t * Dr]);
        }
    }

    float h[16];
    #pragma unroll
    for (int n = 0; n < 16; n++) h[n] = 0.f;
    float S = 0.f;

    #pragma unroll
    for (int t = 0; t < CHUNK; t++) {
        float dv = dtv[t];
        S += dv;
        float cm = dv * xv[t];
        const float4* br4 = (const float4*)(lb + t * Nr);
        float4 q0 = br4[0], q1 = br4[1], q2 = br4[2], q3 = br4[3];
        float bb[16] = {q0.x,q0.y,q0.z,q0.w, q1.x,q1.y,q1.z,q1.w,
                        q2.x,q2.y,q2.z,q2.w, q3.x,q3.y,q3.z,q3.w};
        #pragma unroll
        for (int n = 0; n < 16; n++)
            h[n] = __expf(dv * ac[n]) * h[n] + cm * bb[n];
    }

    Sws[(size_t)(b * NCH + ch) * Dr + d] = S;
    size_t obase = ((size_t)(b * NCH + ch) * Nr) * Dr + d;   // [b][ch][n][d]
    #pragma unroll
    for (int n = 0; n < 16; n++)
        hendws[obase + (size_t)n * Dr] = f2bf(h[n]);
}

// ---------------- K4: combine chunk states sequentially (S-recompute, batch-16) ----------------
// Only 512 waves (2/CU) of parallelism here -> MLP is everything: 8 rounds of
// 32 batched loads (was 16 rounds of 16), exps hoisted out of the fma chain.
__global__ __launch_bounds__(256) void combine_kernel(const float* __restrict__ Sws,
                                                      const unsigned short* __restrict__ hendws,
                                                      const float* __restrict__ A_log,
                                                      unsigned short* __restrict__ hinws) {
    int id = blockIdx.x * 256 + threadIdx.x;  // B*N*D = 32768
    int b  = id >> 14;
    int dn = id & 16383;                      // n*Dr + d
    int n  = dn >> 10;
    int d  = dn & 1023;
    float ac = -__expf(A_log[d * Nr + n]);
    size_t sbase = (size_t)b * NCH * Dr + d;
    size_t base  = (size_t)b * NCH * (Nr * Dr) + dn;
    float hin = 0.f;
    for (int cb = 0; cb < NCH; cb += 16) {
        float p16[16], he[16];
        #pragma unroll
        for (int u = 0; u < 16; u++) {
            p16[u] = Sws[sbase + (size_t)(cb + u) * Dr];
            he[u]  = bf2f(hendws[base + (size_t)(cb + u) * (Nr * Dr)]);
        }
        #pragma unroll
        for (int u = 0; u < 16; u++) p16[u] = __expf(p16[u] * ac);
        #pragma unroll
        for (int u = 0; u < 16; u++) {
            size_t idx = base + (size_t)(cb + u) * (Nr * Dr);
            hinws[idx] = f2bf(hin);
            hin = p16[u] * hin + he[u];
        }
    }
}

// ---------------- K5: scan pass 2 (re-scan with h_in; emit y + D*residual) ----------------
__global__ __launch_bounds__(256) void scan2_kernel(const unsigned short* __restrict__ dtb,
                                                    const unsigned short* __restrict__ xnb,
                                                    const float* __restrict__ bin,
                                                    const float* __restrict__ cin,
                                                    const float* __restrict__ A_log,
                                                    const unsigned short* __restrict__ hinws,
                                                    const float* __restrict__ x,
                                                    const float* __restrict__ Dp,
                                                    float* __restrict__ out) {
    int tid = threadIdx.x;
    int d  = blockIdx.x * 256 + tid;
    int ch = blockIdx.y;
    int b  = blockIdx.z;
    size_t rowbase = (size_t)b * Lr + ch * CHUNK;

    float ac[16];
    #pragma unroll
    for (int i = 0; i < 4; i++) {
        float4 t = ((const float4*)(A_log + (size_t)d * Nr))[i];
        ac[i*4+0] = -__expf(t.x);
        ac[i*4+1] = -__expf(t.y);
        ac[i*4+2] = -__expf(t.z);
        ac[i*4+3] = -__expf(t.w);
    }

    __shared__ float lb[CHUNK * Nr];
    __shared__ float lc[CHUNK * Nr];
    lb[tid] = bin[rowbase * Nr + tid];
    lc[tid] = cin[rowbase * Nr + tid];
    __syncthreads();

    // full register batches in flight
    float dtv[CHUNK], xv[CHUNK];
    {
        const unsigned short* dtp = dtb + rowbase * Dr + d;
        const unsigned short* xp  = xnb + rowbase * Dr + d;
        #pragma unroll
        for (int t = 0; t < CHUNK; t++) {
            dtv[t] = bf2f(dtp[(size_t)t * Dr]);
            xv[t]  = bf2f(xp[(size_t)t * Dr]);
        }
    }

    size_t obase = ((size_t)(b * NCH + ch) * Nr) * Dr + d;
    float h[16];
    #pragma unroll
    for (int n = 0; n < 16; n++) h[n] = bf2f(hinws[obase + (size_t)n * Dr]);

    float dp = Dp[d];
    const float* xr = x   + rowbase * Dr + d;
    float* op       = out + rowbase * Dr + d;

    for (int tb = 0; tb < CHUNK; tb += 4) {
        float xr4[4];
        #pragma unroll
        for (int u = 0; u < 4; u++) xr4[u] = xr[(size_t)(tb + u) * Dr];
        #pragma unroll
        for (int u = 0; u < 4; u++) {
            int t = tb + u;
            float dv = dtv[t];
            float cm = dv * xv[t];
            const float4* br4 = (const float4*)(lb + t * Nr);
            const float4* cr4 = (const float4*)(lc + t * Nr);
            float4 q0 = br4[0], q1 = br4[1], q2 = br4[2], q3 = br4[3];
            float4 r0 = cr4[0], r1 = cr4[1], r2 = cr4[2], r3 = cr4[3];
            float bb[16] = {q0.x,q0.y,q0.z,q0.w, q1.x,q1.y,q1.z,q1.w,
                            q2.x,q2.y,q2.z,q2.w, q3.x,q3.y,q3.z,q3.w};
            float cc[16] = {r0.x,r0.y,r0.z,r0.w, r1.x,r1.y,r1.z,r1.w,
                            r2.x,r2.y,r2.z,r2.w, r3.x,r3.y,r3.z,r3.w};
            float y = 0.f;
            #pragma unroll
            for (int n = 0; n < 16; n++) {
                h[n] = __expf(dv * ac[n]) * h[n] + cm * bb[n];
                y += cc[n] * h[n];
            }
            op[(size_t)t * Dr] = y + dp * xr4[u];
        }
    }
}

// ---------------- host ----------------
extern "C" void kernel_launch(void* const* d_in, const int* in_sizes, int n_in,
                              void* d_out, int out_size, void* d_ws, size_t ws_size,
                              hipStream_t stream) {
    const float* x      = (const float*)d_in[0];
    const float* W_dt   = (const float*)d_in[1];
    const float* b_dt   = (const float*)d_in[2];
    const float* W_B    = (const float*)d_in[3];
    const float* W_C    = (const float*)d_in[4];
    const float* Dparam = (const float*)d_in[5];
    const float* A_log  = (const float*)d_in[6];
    const float* gamma  = (const float*)d_in[7];
    const float* beta   = (const float*)d_in[8];
    float* out = (float*)d_out;

    char* ws = (char*)d_ws;
    unsigned short* xnb  = (unsigned short*)(ws);                     // 8 MB
    unsigned short* wcat = (unsigned short*)(ws + 8388608);           // 2.125 MB
    unsigned short* dtb  = (unsigned short*)(ws + 10616832);          // 8 MB (bf16)
    float*          bin  = (float*)(ws + 19005440);                   // 256 KB
    float*          cin  = (float*)(ws + 19267584);                   // 256 KB
    float*          Sws  = (float*)(ws + 19529728);                   // 1 MB (f32 chunk dt-sums)
    unsigned short* hend = (unsigned short*)(ws + 20578304);          // 8 MB (bf16)
    unsigned short* hin  = (unsigned short*)(ws + 28966912);          // 8 MB  (total ~37 MB)

    ln_pack_kernel<<<M_ROWS + (NPAD * Dr) / 256, 256, 0, stream>>>(
        x, gamma, beta, xnb, W_dt, W_B, W_C, wcat);
    gemm_kernel<<<(M_ROWS / BM) * (NPAD / BN), 256, 0, stream>>>(xnb, wcat, b_dt, dtb, bin, cin);
    dim3 sgrid(Dr / 256, NCH, Bsz);
    scan1_kernel<<<sgrid, 256, 0, stream>>>(dtb, xnb, bin, A_log, Sws, hend);
    combine_kernel<<<(Bsz * Dr * Nr) / 256, 256, 0, stream>>>(Sws, hend, A_log, hin);
    scan2_kernel<<<sgrid, 256, 0, stream>>>(dtb, xnb, bin, cin, A_log, hin, x, Dparam, out);
}